// Round 2
// baseline (327.290 us; speedup 1.0000x reference)
//
#include <hip/hip_runtime.h>
#include <math.h>
#include <stdint.h>

// YOLOv2 loss: pred/target (16,52,52,5,85) fp32 -> scalar fp32.
// Phase 1: thread-per-cell (box decode + IoU + greedy match + box/obj losses).
// Phase 2: 16 lanes per (cell,anchor) slot: class NLL for assigned anchors.

#define NIMG   16
#define NA     5
#define NC     80
#define STRIDE 85                   // 5+C floats per anchor
#define CELLF  (NA * STRIDE)        // 425 floats per cell
#define NCELLS (16 * 52 * 52)       // 43264
#define NANCH  (NCELLS * NA)        // 216320

__device__ __constant__ float AW[5] = {0.57273f, 1.87446f, 3.33843f, 7.88282f, 9.77052f};
__device__ __constant__ float AH[5] = {0.677385f, 2.06253f, 5.47434f, 3.52778f, 9.16828f};

__device__ inline float softplusf(float x) {
    return fmaxf(x, 0.0f) + log1pf(expf(-fabsf(x)));
}
__device__ inline float sigmoidf(float x) { return 1.0f / (1.0f + expf(-x)); }

// ---------------- Phase 1: one thread per cell ----------------
__global__ __launch_bounds__(64) void yolo_phase1(
    const float* __restrict__ pred, const float* __restrict__ target,
    uint32_t* __restrict__ assign_ws, float* __restrict__ out) {
    const int c = blockIdx.x * 64 + threadIdx.x;     // grid covers NCELLS exactly
    const float* P = pred   + (size_t)c * CELLF;
    const float* T = target + (size_t)c * CELLF;

    float sx[NA], sy[NA], ptw[NA], pth[NA], pto[NA];
    float px1[NA], px2[NA], py1[NA], py2[NA];
    float gx1[NA], gx2[NA], gy1[NA], gy2[NA];
    float gobj[NA];
#pragma unroll
    for (int a = 0; a < NA; ++a) {
        const float* pa = P + a * STRIDE;
        const float* ta = T + a * STRIDE;
        sx[a]  = sigmoidf(pa[0]);
        sy[a]  = sigmoidf(pa[1]);
        ptw[a] = pa[2];
        pth[a] = pa[3];
        pto[a] = pa[4];
        float pw = expf(pa[2]) * AW[a];
        float ph = expf(pa[3]) * AH[a];
        px1[a] = sx[a] - pw * 0.5f; px2[a] = sx[a] + pw * 0.5f;
        py1[a] = sy[a] - ph * 0.5f; py2[a] = sy[a] + ph * 0.5f;
        float gw = expf(ta[2]) * AW[a];
        float gh = expf(ta[3]) * AH[a];
        gx1[a] = ta[0] - gw * 0.5f; gx2[a] = ta[0] + gw * 0.5f;
        gy1[a] = ta[1] - gh * 0.5f; gy2[a] = ta[1] + gh * 0.5f;
        gobj[a] = ta[4];
    }

    float iou[NA][NA];
#pragma unroll
    for (int g = 0; g < NA; ++g) {
        float gA = (gx2[g] - gx1[g]) * (gy2[g] - gy1[g]);
#pragma unroll
        for (int p = 0; p < NA; ++p) {
            float iw = fmaxf(fminf(gx2[g], px2[p]) - fmaxf(gx1[g], px1[p]), 0.0f);
            float ih = fmaxf(fminf(gy2[g], py2[p]) - fmaxf(gy1[g], py1[p]), 0.0f);
            float inter = iw * ih;
            float pA = (px2[p] - px1[p]) * (py2[p] - py1[p]);
            iou[g][p] = inter / (gA + pA - inter + 1e-9f);
        }
    }

    // greedy matching: first-occurrence argmax, taken anchors masked to -1
    int assign[NA] = {-1, -1, -1, -1, -1};
    bool taken[NA] = {false, false, false, false, false};
#pragma unroll
    for (int g = 0; g < NA; ++g) {
        if (gobj[g] > 0.5f) {
            float best = -2.0f; int bi = 0;
#pragma unroll
            for (int p = 0; p < NA; ++p) {
                float v = taken[p] ? -1.0f : iou[g][p];
                if (v > best) { best = v; bi = p; }
            }
            taken[bi] = true;
            assign[bi] = g;
        }
    }

    // pack assignment (g+1 in 4 bits per anchor) for phase 2
    uint32_t word = 0;
#pragma unroll
    for (int p = 0; p < NA; ++p) word |= (uint32_t)(assign[p] + 1) << (4 * p);
    assign_ws[c] = word;

    // box + objectness losses
    float l_xy = 0.f, l_wh = 0.f, l_obj = 0.f, l_noobj = 0.f;
#pragma unroll
    for (int p = 0; p < NA; ++p) {
        const int g = assign[p];
        if (g >= 0) {
            const float* tg = T + g * STRIDE;
            float dx = sx[p] - tg[0];
            float dy = sy[p] - tg[1];
            l_xy += dx * dx + dy * dy;
            float dw = ptw[p] - tg[2];
            float dh = pth[p] - tg[3];
            l_wh += dw * dw + dh * dh;
            l_obj += softplusf(-pto[p]);
        } else {
            l_noobj += softplusf(pto[p]);
        }
    }
    float cellLoss = 5.0f * l_xy + 5.0f * l_wh + 1.0f * l_obj + 0.5f * l_noobj;

    // wave-reduce 64 cells -> one atomic per block
#pragma unroll
    for (int o = 32; o; o >>= 1) cellLoss += __shfl_xor(cellLoss, o);
    if (threadIdx.x == 0) atomicAdd(out, cellLoss * (1.0f / (float)NIMG));
}

// ---------------- Phase 2: 16 lanes per (cell, anchor) ----------------
__global__ __launch_bounds__(256) void yolo_phase2(
    const float* __restrict__ pred, const float* __restrict__ target,
    const uint32_t* __restrict__ assign_ws, float* __restrict__ out) {
    __shared__ float bsum;
    const int tid = threadIdx.x;
    if (tid == 0) bsum = 0.f;
    __syncthreads();

    const int gi   = blockIdx.x * 16 + (tid >> 4);   // grid covers NANCH exactly
    const int lane = tid & 15;
    const int c = gi / NA;
    const int p = gi - c * NA;
    const uint32_t word = assign_ws[c];
    const int g = (int)((word >> (4 * p)) & 0xFu) - 1;

    if (g >= 0) {
        const float* pc = pred   + (size_t)c * CELLF + p * STRIDE + 5;
        const float* tc = target + (size_t)c * CELLF + g * STRIDE + 5;
        float pv[5], tv[5];
#pragma unroll
        for (int k = 0; k < 5; ++k) {
            pv[k] = pc[lane + 16 * k];
            tv[k] = tc[lane + 16 * k];
        }
        // logsumexp over 80 pred logits
        float m = fmaxf(fmaxf(fmaxf(pv[0], pv[1]), fmaxf(pv[2], pv[3])), pv[4]);
#pragma unroll
        for (int o = 1; o < 16; o <<= 1) m = fmaxf(m, __shfl_xor(m, o));
        float s = 0.f;
#pragma unroll
        for (int k = 0; k < 5; ++k) s += expf(pv[k] - m);
#pragma unroll
        for (int o = 1; o < 16; o <<= 1) s += __shfl_xor(s, o);
        float lse = m + logf(s);

        // first-occurrence argmax of target cls, carrying the pred logit
        float bt = tv[0]; int bi = lane; float bp = pv[0];
#pragma unroll
        for (int k = 1; k < 5; ++k) {
            if (tv[k] > bt) { bt = tv[k]; bi = lane + 16 * k; bp = pv[k]; }
        }
#pragma unroll
        for (int o = 1; o < 16; o <<= 1) {
            float ot = __shfl_xor(bt, o);
            int   oi = __shfl_xor(bi, o);
            float op = __shfl_xor(bp, o);
            if (ot > bt || (ot == bt && oi < bi)) { bt = ot; bi = oi; bp = op; }
        }
        if (lane == 0) atomicAdd(&bsum, lse - bp);
    }
    __syncthreads();
    if (tid == 0 && bsum != 0.f) atomicAdd(out, bsum * (1.0f / (float)NIMG));
}

extern "C" void kernel_launch(void* const* d_in, const int* in_sizes, int n_in,
                              void* d_out, int out_size, void* d_ws, size_t ws_size,
                              hipStream_t stream) {
    const float* pred   = (const float*)d_in[0];
    const float* target = (const float*)d_in[1];
    float* out = (float*)d_out;
    uint32_t* assign_ws = (uint32_t*)d_ws;   // NCELLS * 4 bytes = 173 KB

    hipMemsetAsync(out, 0, (size_t)out_size * sizeof(float), stream);
    yolo_phase1<<<NCELLS / 64, 64, 0, stream>>>(pred, target, assign_ws, out);
    yolo_phase2<<<NANCH / 16, 256, 0, stream>>>(pred, target, assign_ws, out);
}

// Round 5
// 183.864 us; speedup vs baseline: 1.7801x; 1.7801x over previous
//
#include <hip/hip_runtime.h>
#include <math.h>
#include <stdint.h>

// YOLOv2 loss: pred/target (16,52,52,5,85) fp32 -> scalar fp32.
// K1: 320-thread blocks, 64 cells each. Thread-per-anchor decode -> LDS,
//     wave 0 does greedy match + box/obj losses. Block partial -> ws.
// K3: 16 lanes per anchor: class NLL for assigned anchors. Block partial -> ws.
// K4: one block reduces all partials -> out. NO same-address global atomics.

#define NIMG   16
#define NA     5
#define NC     80
#define STRIDE 85                    // 5+C floats per anchor
#define CELLF  (NA * STRIDE)         // 425
#define NCELLS 43264                 // 16*52*52
#define NANCH  (NCELLS * NA)         // 216320

#define K1_CELLS   64
#define K1_THREADS 320               // 5 waves; one thread per anchor
#define K1_BLOCKS  (NCELLS / K1_CELLS)   // 676
#define K3_BLOCKS  (NANCH / 16)          // 13520
#define NPART      (K1_BLOCKS + K3_BLOCKS)

__device__ __constant__ float AW[5] = {0.57273f, 1.87446f, 3.33843f, 7.88282f, 9.77052f};
__device__ __constant__ float AH[5] = {0.677385f, 2.06253f, 5.47434f, 3.52778f, 9.16828f};

__device__ inline float softplusf(float x) {
    return fmaxf(x, 0.0f) + log1pf(expf(-fabsf(x)));
}
__device__ inline float sigmoidf(float x) { return 1.0f / (1.0f + expf(-x)); }

// ---------------- K1: decode + match + box/obj losses ----------------
__global__ __launch_bounds__(K1_THREADS) void yolo_k1(
    const float* __restrict__ pred, const float* __restrict__ target,
    uint32_t* __restrict__ assign_ws, float* __restrict__ part_ws) {
    __shared__ float s_px1[K1_THREADS], s_px2[K1_THREADS], s_py1[K1_THREADS], s_py2[K1_THREADS], s_pA[K1_THREADS];
    __shared__ float s_gx1[K1_THREADS], s_gx2[K1_THREADS], s_gy1[K1_THREADS], s_gy2[K1_THREADS], s_gA[K1_THREADS];
    __shared__ float s_gobj[K1_THREADS];
    __shared__ float s_sx[K1_THREADS], s_sy[K1_THREADS], s_ptw[K1_THREADS], s_pth[K1_THREADS];
    __shared__ float s_spn[K1_THREADS], s_spp[K1_THREADS];
    __shared__ float s_tx[K1_THREADS], s_ty[K1_THREADS], s_tw[K1_THREADS], s_th[K1_THREADS];

    const int t = threadIdx.x;
    const int ga = blockIdx.x * K1_THREADS + t;        // global anchor index
    const int a = t % NA;                              // anchor slot in cell
    const float* pa = pred   + (size_t)ga * STRIDE;
    const float* ta = target + (size_t)ga * STRIDE;
    const float p0 = pa[0], p1 = pa[1], p2 = pa[2], p3 = pa[3], p4 = pa[4];
    const float t0 = ta[0], t1 = ta[1], t2 = ta[2], t3 = ta[3], t4 = ta[4];
    const float aw = AW[a], ah = AH[a];

    const float sx = sigmoidf(p0);
    const float sy = sigmoidf(p1);
    const float pw = expf(p2) * aw, ph = expf(p3) * ah;
    const float gw = expf(t2) * aw, gh = expf(t3) * ah;

    s_px1[t] = sx - pw * 0.5f;  s_px2[t] = sx + pw * 0.5f;
    s_py1[t] = sy - ph * 0.5f;  s_py2[t] = sy + ph * 0.5f;
    s_pA[t]  = pw * ph;
    s_gx1[t] = t0 - gw * 0.5f;  s_gx2[t] = t0 + gw * 0.5f;
    s_gy1[t] = t1 - gh * 0.5f;  s_gy2[t] = t1 + gh * 0.5f;
    s_gA[t]  = gw * gh;
    s_gobj[t] = t4;
    s_sx[t] = sx;  s_sy[t] = sy;  s_ptw[t] = p2;  s_pth[t] = p3;
    s_spn[t] = softplusf(-p4);    s_spp[t] = softplusf(p4);
    s_tx[t] = t0;  s_ty[t] = t1;  s_tw[t] = t2;  s_th[t] = t3;
    __syncthreads();

    float cellLoss = 0.0f;
    if (t < 64) {                                      // wave 0: one cell per lane
        const int la = t * NA;
        float iou[NA][NA];
#pragma unroll
        for (int g = 0; g < NA; ++g) {
            const float gx1 = s_gx1[la+g], gx2 = s_gx2[la+g];
            const float gy1 = s_gy1[la+g], gy2 = s_gy2[la+g];
            const float gA  = s_gA[la+g];
#pragma unroll
            for (int p = 0; p < NA; ++p) {
                float iw = fmaxf(fminf(gx2, s_px2[la+p]) - fmaxf(gx1, s_px1[la+p]), 0.0f);
                float ih = fmaxf(fminf(gy2, s_py2[la+p]) - fmaxf(gy1, s_py1[la+p]), 0.0f);
                float inter = iw * ih;
                iou[g][p] = inter / (gA + s_pA[la+p] - inter + 1e-9f);
            }
        }
        int assign[NA] = {-1, -1, -1, -1, -1};
        bool taken[NA] = {false, false, false, false, false};
#pragma unroll
        for (int g = 0; g < NA; ++g) {
            if (s_gobj[la+g] > 0.5f) {
                float best = -2.0f; int bi = 0;
#pragma unroll
                for (int p = 0; p < NA; ++p) {
                    float v = taken[p] ? -1.0f : iou[g][p];
                    if (v > best) { best = v; bi = p; }
                }
                taken[bi] = true;
                assign[bi] = g;
            }
        }
        uint32_t word = 0;
        float l_xy = 0.f, l_wh = 0.f, l_obj = 0.f, l_noobj = 0.f;
#pragma unroll
        for (int p = 0; p < NA; ++p) {
            const int g = assign[p];
            word |= (uint32_t)(g + 1) << (4 * p);
            if (g >= 0) {
                float dx = s_sx[la+p] - s_tx[la+g];
                float dy = s_sy[la+p] - s_ty[la+g];
                l_xy += dx * dx + dy * dy;
                float dw = s_ptw[la+p] - s_tw[la+g];
                float dh = s_pth[la+p] - s_th[la+g];
                l_wh += dw * dw + dh * dh;
                l_obj += s_spn[la+p];
            } else {
                l_noobj += s_spp[la+p];
            }
        }
        assign_ws[blockIdx.x * K1_CELLS + t] = word;
        cellLoss = 5.0f * l_xy + 5.0f * l_wh + 1.0f * l_obj + 0.5f * l_noobj;
#pragma unroll
        for (int o = 32; o; o >>= 1) cellLoss += __shfl_xor(cellLoss, o);
        if (t == 0) part_ws[blockIdx.x] = cellLoss;
    }
}

// ---------------- K3: class NLL, 16 lanes per anchor ----------------
__global__ __launch_bounds__(256) void yolo_k3(
    const float* __restrict__ pred, const float* __restrict__ target,
    const uint32_t* __restrict__ assign_ws, float* __restrict__ part_ws) {
    __shared__ float wsum[4];
    const int tid  = threadIdx.x;
    const int gi   = blockIdx.x * 16 + (tid >> 4);
    const int lane = tid & 15;
    const int c = gi / NA;
    const int p = gi - c * NA;
    const int g = (int)((assign_ws[c] >> (4 * p)) & 0xFu) - 1;

    float contrib = 0.0f;
    if (g >= 0) {
        const float* pc = pred   + (size_t)c * CELLF + p * STRIDE + 5;
        const float* tc = target + (size_t)c * CELLF + g * STRIDE + 5;
        float pv[5], tv[5];
#pragma unroll
        for (int k = 0; k < 5; ++k) {
            pv[k] = pc[lane + 16 * k];
            tv[k] = tc[lane + 16 * k];
        }
        float m = fmaxf(fmaxf(fmaxf(pv[0], pv[1]), fmaxf(pv[2], pv[3])), pv[4]);
#pragma unroll
        for (int o = 1; o < 16; o <<= 1) m = fmaxf(m, __shfl_xor(m, o));
        float s = 0.f;
#pragma unroll
        for (int k = 0; k < 5; ++k) s += expf(pv[k] - m);
#pragma unroll
        for (int o = 1; o < 16; o <<= 1) s += __shfl_xor(s, o);
        float lse = m + logf(s);

        float bt = tv[0]; int bi = lane; float bp = pv[0];
#pragma unroll
        for (int k = 1; k < 5; ++k) {
            if (tv[k] > bt) { bt = tv[k]; bi = lane + 16 * k; bp = pv[k]; }
        }
#pragma unroll
        for (int o = 1; o < 16; o <<= 1) {
            float ot = __shfl_xor(bt, o);
            int   oi = __shfl_xor(bi, o);
            float op = __shfl_xor(bp, o);
            if (ot > bt || (ot == bt && oi < bi)) { bt = ot; bi = oi; bp = op; }
        }
        contrib = (lane == 0) ? (lse - bp) : 0.0f;
    }
    // sum the 4 group-leaders (lanes 0,16,32,48) of this wave
    contrib += __shfl_xor(contrib, 16);
    contrib += __shfl_xor(contrib, 32);
    if ((tid & 63) == 0) wsum[tid >> 6] = contrib;
    __syncthreads();
    if (tid == 0)
        part_ws[K1_BLOCKS + blockIdx.x] = wsum[0] + wsum[1] + wsum[2] + wsum[3];
}

// ---------------- K4: final reduction ----------------
__global__ __launch_bounds__(256) void yolo_k4(
    const float* __restrict__ part_ws, float* __restrict__ out) {
    __shared__ float ws4[4];
    float s = 0.0f;
    for (int i = threadIdx.x; i < NPART; i += 256) s += part_ws[i];
#pragma unroll
    for (int o = 32; o; o >>= 1) s += __shfl_xor(s, o);
    if ((threadIdx.x & 63) == 0) ws4[threadIdx.x >> 6] = s;
    __syncthreads();
    if (threadIdx.x == 0)
        out[0] = (ws4[0] + ws4[1] + ws4[2] + ws4[3]) * (1.0f / (float)NIMG);
}

extern "C" void kernel_launch(void* const* d_in, const int* in_sizes, int n_in,
                              void* d_out, int out_size, void* d_ws, size_t ws_size,
                              hipStream_t stream) {
    const float* pred   = (const float*)d_in[0];
    const float* target = (const float*)d_in[1];
    float* out = (float*)d_out;
    uint32_t* assign_ws = (uint32_t*)d_ws;                   // NCELLS words
    float* part_ws = (float*)d_ws + NCELLS;                  // NPART floats

    yolo_k1<<<K1_BLOCKS, K1_THREADS, 0, stream>>>(pred, target, assign_ws, part_ws);
    yolo_k3<<<K3_BLOCKS, 256, 0, stream>>>(pred, target, assign_ws, part_ws);
    yolo_k4<<<1, 256, 0, stream>>>(part_ws, out);
}

// Round 14
// 170.097 us; speedup vs baseline: 1.9241x; 1.0809x over previous
//
#include <hip/hip_runtime.h>
#include <math.h>
#include <stdint.h>

// YOLOv2 loss: pred/target (16,52,52,5,85) fp32 -> scalar fp32.
// Fused kernel: 256-thread block owns 32 cells end-to-end.
//   - threads 0..159: thread-per-anchor box decode -> LDS
//   - lanes 0..31 of wave 0: greedy IoU matching + box/obj losses (assignment in LDS)
//   - 16 groups x 16 lanes: class NLL (LSE-80 + target argmax-80) for assigned anchors
//   - block partial -> part_ws;  K4: one block reduces 1352 partials -> out.
// No global same-address atomics; no inter-kernel assignment round-trip.

#define NIMG   16
#define NA     5
#define STRIDE 85                    // 5+80 floats per anchor
#define CELLF  (NA * STRIDE)         // 425
#define NCELLS 43264                 // 16*52*52
#define CPB    32                    // cells per block
#define BT     256                   // threads per block
#define NANCHB (CPB * NA)            // 160 anchors per block
#define NB     (NCELLS / CPB)        // 1352 blocks

__device__ __constant__ float AW[5] = {0.57273f, 1.87446f, 3.33843f, 7.88282f, 9.77052f};
__device__ __constant__ float AH[5] = {0.677385f, 2.06253f, 5.47434f, 3.52778f, 9.16828f};

__device__ inline float softplusf(float x) {
    return fmaxf(x, 0.0f) + log1pf(expf(-fabsf(x)));
}
__device__ inline float sigmoidf(float x) { return 1.0f / (1.0f + expf(-x)); }

__global__ __launch_bounds__(BT) void yolo_fused(
    const float* __restrict__ pred, const float* __restrict__ target,
    float* __restrict__ part_ws) {
    __shared__ float s_px1[NANCHB], s_px2[NANCHB], s_py1[NANCHB], s_py2[NANCHB], s_pA[NANCHB];
    __shared__ float s_gx1[NANCHB], s_gx2[NANCHB], s_gy1[NANCHB], s_gy2[NANCHB], s_gA[NANCHB];
    __shared__ float s_gobj[NANCHB];
    __shared__ float s_sx[NANCHB], s_sy[NANCHB], s_ptw[NANCHB], s_pth[NANCHB];
    __shared__ float s_spn[NANCHB], s_spp[NANCHB];
    __shared__ float s_tx[NANCHB], s_ty[NANCHB], s_tw[NANCHB], s_th[NANCHB];
    __shared__ uint32_t s_assign[CPB];
    __shared__ float s_wpart[BT / 64];

    const int t = threadIdx.x;

    // ---- decode: one thread per anchor (threads 0..159) ----
    if (t < NANCHB) {
        const int ga = blockIdx.x * NANCHB + t;        // global anchor index
        const int a = t % NA;
        const float* pa = pred   + (size_t)ga * STRIDE;
        const float* ta = target + (size_t)ga * STRIDE;
        const float p0 = pa[0], p1 = pa[1], p2 = pa[2], p3 = pa[3], p4 = pa[4];
        const float t0 = ta[0], t1 = ta[1], t2 = ta[2], t3 = ta[3], t4 = ta[4];
        const float aw = AW[a], ah = AH[a];

        const float sx = sigmoidf(p0);
        const float sy = sigmoidf(p1);
        const float pw = expf(p2) * aw, ph = expf(p3) * ah;
        const float gw = expf(t2) * aw, gh = expf(t3) * ah;

        s_px1[t] = sx - pw * 0.5f;  s_px2[t] = sx + pw * 0.5f;
        s_py1[t] = sy - ph * 0.5f;  s_py2[t] = sy + ph * 0.5f;
        s_pA[t]  = pw * ph;
        s_gx1[t] = t0 - gw * 0.5f;  s_gx2[t] = t0 + gw * 0.5f;
        s_gy1[t] = t1 - gh * 0.5f;  s_gy2[t] = t1 + gh * 0.5f;
        s_gA[t]  = gw * gh;
        s_gobj[t] = t4;
        s_sx[t] = sx;  s_sy[t] = sy;  s_ptw[t] = p2;  s_pth[t] = p3;
        s_spn[t] = softplusf(-p4);    s_spp[t] = softplusf(p4);
        s_tx[t] = t0;  s_ty[t] = t1;  s_tw[t] = t2;  s_th[t] = t3;
    }
    __syncthreads();

    // ---- matching + box/obj losses: lane-per-cell (threads 0..31) ----
    float loss = 0.0f;                                  // per-thread contribution
    if (t < CPB) {
        const int la = t * NA;                          // stride 5: gcd(5,32)=1, conflict-free
        float iou[NA][NA];
#pragma unroll
        for (int g = 0; g < NA; ++g) {
            const float gx1 = s_gx1[la+g], gx2 = s_gx2[la+g];
            const float gy1 = s_gy1[la+g], gy2 = s_gy2[la+g];
            const float gA  = s_gA[la+g];
#pragma unroll
            for (int p = 0; p < NA; ++p) {
                float iw = fmaxf(fminf(gx2, s_px2[la+p]) - fmaxf(gx1, s_px1[la+p]), 0.0f);
                float ih = fmaxf(fminf(gy2, s_py2[la+p]) - fmaxf(gy1, s_py1[la+p]), 0.0f);
                float inter = iw * ih;
                iou[g][p] = inter / (gA + s_pA[la+p] - inter + 1e-9f);
            }
        }
        int assign[NA] = {-1, -1, -1, -1, -1};
        bool taken[NA] = {false, false, false, false, false};
#pragma unroll
        for (int g = 0; g < NA; ++g) {
            if (s_gobj[la+g] > 0.5f) {
                float best = -2.0f; int bi = 0;
#pragma unroll
                for (int p = 0; p < NA; ++p) {
                    float v = taken[p] ? -1.0f : iou[g][p];
                    if (v > best) { best = v; bi = p; }
                }
                taken[bi] = true;
                assign[bi] = g;
            }
        }
        uint32_t word = 0;
        float l_xy = 0.f, l_wh = 0.f, l_obj = 0.f, l_noobj = 0.f;
#pragma unroll
        for (int p = 0; p < NA; ++p) {
            const int g = assign[p];
            word |= (uint32_t)(g + 1) << (4 * p);
            if (g >= 0) {
                float dx = s_sx[la+p] - s_tx[la+g];
                float dy = s_sy[la+p] - s_ty[la+g];
                l_xy += dx * dx + dy * dy;
                float dw = s_ptw[la+p] - s_tw[la+g];
                float dh = s_pth[la+p] - s_th[la+g];
                l_wh += dw * dw + dh * dh;
                l_obj += s_spn[la+p];
            } else {
                l_noobj += s_spp[la+p];
            }
        }
        s_assign[t] = word;
        loss = 5.0f * l_xy + 5.0f * l_wh + 1.0f * l_obj + 0.5f * l_noobj;
    }
    __syncthreads();

    // ---- class NLL: 16 groups x 16 lanes; group j owns cells 2j, 2j+1 (10 slots) ----
    const int grp = t >> 4;
    const int ln  = t & 15;
#pragma unroll
    for (int si = 0; si < 10; ++si) {
        const int slot = grp * 10 + si;
        const int cell = slot / NA;
        const int p    = slot - cell * NA;
        const int g    = (int)((s_assign[cell] >> (4 * p)) & 0xFu) - 1;
        if (g >= 0) {                                   // uniform across the 16-lane group
            const size_t cbase = ((size_t)blockIdx.x * CPB + cell) * CELLF;
            const float* pc = pred   + cbase + p * STRIDE + 5;
            const float* tc = target + cbase + g * STRIDE + 5;
            float pv[5], tv[5];
#pragma unroll
            for (int k = 0; k < 5; ++k) {
                pv[k] = pc[ln + 16 * k];
                tv[k] = tc[ln + 16 * k];
            }
            float m = fmaxf(fmaxf(fmaxf(pv[0], pv[1]), fmaxf(pv[2], pv[3])), pv[4]);
#pragma unroll
            for (int o = 1; o < 16; o <<= 1) m = fmaxf(m, __shfl_xor(m, o));
            float s = 0.f;
#pragma unroll
            for (int k = 0; k < 5; ++k) s += expf(pv[k] - m);
#pragma unroll
            for (int o = 1; o < 16; o <<= 1) s += __shfl_xor(s, o);
            float lse = m + logf(s);

            float bt = tv[0]; int bi = ln; float bp = pv[0];
#pragma unroll
            for (int k = 1; k < 5; ++k) {
                if (tv[k] > bt) { bt = tv[k]; bi = ln + 16 * k; bp = pv[k]; }
            }
#pragma unroll
            for (int o = 1; o < 16; o <<= 1) {
                float ot = __shfl_xor(bt, o);
                int   oi = __shfl_xor(bi, o);
                float op = __shfl_xor(bp, o);
                if (ot > bt || (ot == bt && oi < bi)) { bt = ot; bi = oi; bp = op; }
            }
            if (ln == 0) loss += lse - bp;              // L_CLS = 1.0
        }
    }

    // ---- block reduction: wave shuffle -> LDS -> thread 0 ----
#pragma unroll
    for (int o = 32; o; o >>= 1) loss += __shfl_xor(loss, o);
    if ((t & 63) == 0) s_wpart[t >> 6] = loss;
    __syncthreads();
    if (t == 0)
        part_ws[blockIdx.x] = s_wpart[0] + s_wpart[1] + s_wpart[2] + s_wpart[3];
}

// ---- final reduction: one block over NB partials ----
__global__ __launch_bounds__(256) void yolo_reduce(
    const float* __restrict__ part_ws, float* __restrict__ out) {
    __shared__ float ws4[4];
    float s = 0.0f;
    for (int i = threadIdx.x; i < NB; i += 256) s += part_ws[i];
#pragma unroll
    for (int o = 32; o; o >>= 1) s += __shfl_xor(s, o);
    if ((threadIdx.x & 63) == 0) ws4[threadIdx.x >> 6] = s;
    __syncthreads();
    if (threadIdx.x == 0)
        out[0] = (ws4[0] + ws4[1] + ws4[2] + ws4[3]) * (1.0f / (float)NIMG);
}

extern "C" void kernel_launch(void* const* d_in, const int* in_sizes, int n_in,
                              void* d_out, int out_size, void* d_ws, size_t ws_size,
                              hipStream_t stream) {
    const float* pred   = (const float*)d_in[0];
    const float* target = (const float*)d_in[1];
    float* out = (float*)d_out;
    float* part_ws = (float*)d_ws;                     // NB floats (5.4 KB)

    yolo_fused<<<NB, BT, 0, stream>>>(pred, target, part_ws);
    yolo_reduce<<<1, 256, 0, stream>>>(part_ws, out);
}